// Round 1
// baseline (6063.701 us; speedup 1.0000x reference)
//
#include <hip/hip_runtime.h>

#define HH 512
#define II 256
#define TT 512
#define BB 64

typedef unsigned short u16;
typedef unsigned int u32;
typedef __bf16 bf16x8 __attribute__((ext_vector_type(8)));
typedef u16 u16x8 __attribute__((ext_vector_type(8)));
typedef float f32x4 __attribute__((ext_vector_type(4)));

struct GruParams {
  const float* Wih[4];  // cell order: 0=f0, 1=b0, 2=f1, 3=b1
  const float* Whh[4];
  const float* bih[4];
  const float* bhh[4];
  const u16* xbf;   // [64][512][256] bf16
  u16* hbuf;        // [4 cells][2 parity][64][512] bf16
  u32* bar;         // [4 domains][64 u32]
  float* out;       // 64*512*1024 + 64*1024
};

__device__ __forceinline__ u16 f2bf(float f) {
  u32 u = __builtin_bit_cast(u32, f);
  u += 0x7fffu + ((u >> 16) & 1u);
  return (u16)(u >> 16);
}

__device__ __forceinline__ float sigm(float x) {
  return 1.0f / (1.0f + __expf(-x));
}

__device__ __forceinline__ float tanh_s(float x) {
  float t = __expf(-2.0f * fabsf(x));
  float r = (1.0f - t) / (1.0f + t);
  return copysignf(r, x);
}

__global__ void cvt_x(const float* __restrict__ x, u16* __restrict__ xb) {
  const int i = blockIdx.x * blockDim.x + threadIdx.x;
  const float4 v = reinterpret_cast<const float4*>(x)[i];
  ushort4 o;
  o.x = f2bf(v.x); o.y = f2bf(v.y); o.z = f2bf(v.z); o.w = f2bf(v.w);
  reinterpret_cast<ushort4*>(xb)[i] = o;
}

// 256 WGs: wg = cell(2b) | m(2b) | c(4b). 4 waves/WG: wid 0=r, 1=z, 2=i_n, 3=h_n.
__global__ __launch_bounds__(256, 1) void gru_persist(GruParams p) {
  const int tid  = threadIdx.x;
  const int lane = tid & 63;
  const int wid  = tid >> 6;
  const int wg   = blockIdx.x;
  const int cell = wg & 3;
  const int mm   = (wg >> 2) & 3;
  const int cc   = wg >> 4;
  const int KIN  = (cell < 2) ? II : HH;
  const int n16  = lane & 15;
  const int kg   = (lane >> 4) & 3;
  const int koff = kg * 8;
  const int gb   = (wid == 0) ? 0 : (wid == 1) ? HH : 2 * HH;
  const int nbase = gb + cc * 32;

  int nk, inp_end;
  if (wid < 2)       { nk = (KIN + HH) / 32; inp_end = KIN; }
  else if (wid == 2) { nk = KIN / 32;        inp_end = KIN; }
  else               { nk = HH / 32;         inp_end = 0;   }

  float bias0, bias1;
  {
    const int n0 = nbase + n16, n1 = nbase + 16 + n16;
    if (wid < 2)       { bias0 = p.bih[cell][n0] + p.bhh[cell][n0];
                         bias1 = p.bih[cell][n1] + p.bhh[cell][n1]; }
    else if (wid == 2) { bias0 = p.bih[cell][n0]; bias1 = p.bih[cell][n1]; }
    else               { bias0 = p.bhh[cell][n0]; bias1 = p.bhh[cell][n1]; }
  }

  // ---- persistent weight fragments in VGPRs: wf[ks][ntile], B[k][n] layout ----
  bf16x8 wf[32][2];
  {
    const float* Wih = p.Wih[cell];
    const float* Whh = p.Whh[cell];
    #pragma unroll
    for (int ks = 0; ks < 32; ++ks) {
      if (ks < nk) {
        const int kk = ks * 32;
        #pragma unroll
        for (int j = 0; j < 2; ++j) {
          const int r = nbase + 16 * j + n16;
          u16x8 t;
          if (kk < inp_end) {
            const int col = kk + koff;
            if (cell == 1) {  // b0: feature-flipped input -> flip Wih columns
              #pragma unroll
              for (int e = 0; e < 8; ++e)
                t[e] = f2bf(Wih[r * KIN + (KIN - 1 - (col + e))]);
            } else {
              const float4 a = *reinterpret_cast<const float4*>(Wih + r * KIN + col);
              const float4 b = *reinterpret_cast<const float4*>(Wih + r * KIN + col + 4);
              t[0]=f2bf(a.x); t[1]=f2bf(a.y); t[2]=f2bf(a.z); t[3]=f2bf(a.w);
              t[4]=f2bf(b.x); t[5]=f2bf(b.y); t[6]=f2bf(b.z); t[7]=f2bf(b.w);
            }
          } else {
            const int col = kk - inp_end + koff;
            const float4 a = *reinterpret_cast<const float4*>(Whh + r * HH + col);
            const float4 b = *reinterpret_cast<const float4*>(Whh + r * HH + col + 4);
            t[0]=f2bf(a.x); t[1]=f2bf(a.y); t[2]=f2bf(a.z); t[3]=f2bf(a.w);
            t[4]=f2bf(b.x); t[5]=f2bf(b.y); t[6]=f2bf(b.z); t[7]=f2bf(b.w);
          }
          wf[ks][j] = __builtin_bit_cast(bf16x8, t);
        }
        __builtin_amdgcn_sched_barrier(0);
      }
    }
  }

  __shared__ float gsm[4][16][32];
  u32* cnt = p.bar + mm * 64;
  const int brow = mm * 16 + n16;   // this lane's A-operand batch row
  float h0r = 0.0f, h1r = 0.0f;     // fp32 master h for this thread's 2 elements

  for (int s = 0; s <= TT; ++s) {
    const int tc = (cell < 2) ? s : s - 1;   // layer-1 runs one step skewed
    const bool active = (tc >= 0) && (tc < TT);
    if (active) {
      const u16* inp_base = (cell < 2)
        ? p.xbf + (size_t)(brow * TT + tc) * II
        : p.hbuf + (size_t)(((cell - 2) * 2 + (tc & 1)) * BB + brow) * HH;
      const u16* own_base =
          p.hbuf + (size_t)((cell * 2 + ((tc & 1) ^ 1)) * BB + brow) * HH;

      f32x4 acc00 = {bias0, bias0, bias0, bias0};
      f32x4 acc01 = {bias1, bias1, bias1, bias1};
      f32x4 acc10 = {0.f, 0.f, 0.f, 0.f};
      f32x4 acc11 = {0.f, 0.f, 0.f, 0.f};

      #pragma unroll
      for (int blk = 0; blk < 4; ++blk) {
        if (blk * 256 < nk * 32) {
          const int kb = blk * 256;
          const u16* bp = (kb < inp_end) ? (inp_base + kb + koff)
                                         : (own_base + (kb - inp_end) + koff);
          #pragma unroll
          for (int u = 0; u < 8; ++u) {
            const bf16x8 af = __builtin_bit_cast(bf16x8,
                *reinterpret_cast<const uint4*>(bp + u * 32));
            if (u & 1) {
              acc10 = __builtin_amdgcn_mfma_f32_16x16x32_bf16(af, wf[blk*8+u][0], acc10, 0, 0, 0);
              acc11 = __builtin_amdgcn_mfma_f32_16x16x32_bf16(af, wf[blk*8+u][1], acc11, 0, 0, 0);
            } else {
              acc00 = __builtin_amdgcn_mfma_f32_16x16x32_bf16(af, wf[blk*8+u][0], acc00, 0, 0, 0);
              acc01 = __builtin_amdgcn_mfma_f32_16x16x32_bf16(af, wf[blk*8+u][1], acc01, 0, 0, 0);
            }
          }
        }
      }
      #pragma unroll
      for (int i = 0; i < 4; ++i) {
        gsm[wid][kg * 4 + i][n16]      = acc00[i] + acc10[i];
        gsm[wid][kg * 4 + i][16 + n16] = acc01[i] + acc11[i];
      }
    }
    __syncthreads();
    if (active) {
      #pragma unroll
      for (int q = 0; q < 2; ++q) {
        const int e = tid + q * 256;
        const int row = e >> 5, col = e & 31;
        const float rr = sigm(gsm[0][row][col]);
        const float zz = sigm(gsm[1][row][col]);
        const float nn = tanh_s(gsm[2][row][col] + rr * gsm[3][row][col]);
        const float hp = q ? h1r : h0r;
        const float hn = (1.0f - zz) * nn + zz * hp;
        if (q) h1r = hn; else h0r = hn;
        const int gbrow = mm * 16 + row;
        const int hc = cc * 32 + col;
        p.hbuf[(size_t)((cell * 2 + (tc & 1)) * BB + gbrow) * HH + hc] = f2bf(hn);
        if (cell >= 2) {
          const int jb = (cell == 2) ? hc : HH + hc;
          p.out[(size_t)(gbrow * TT + tc) * 1024 + jb] = hn;
          if (tc == TT - 1)
            p.out[(size_t)BB * TT * 1024 + (size_t)gbrow * 1024 + jb] = hn;
        }
      }
    }
    // ---- per-m-domain barrier (64 WGs), monotonic counter, agent scope ----
    __syncthreads();
    if (tid == 0) {
      __hip_atomic_fetch_add(cnt, 1u, __ATOMIC_RELEASE, __HIP_MEMORY_SCOPE_AGENT);
      const u32 tgt = 64u * (u32)(s + 1);
      while (__hip_atomic_load(cnt, __ATOMIC_RELAXED, __HIP_MEMORY_SCOPE_AGENT) < tgt)
        __builtin_amdgcn_s_sleep(1);
      (void)__hip_atomic_load(cnt, __ATOMIC_ACQUIRE, __HIP_MEMORY_SCOPE_AGENT);
    }
    __syncthreads();
  }
}

extern "C" void kernel_launch(void* const* d_in, const int* in_sizes, int n_in,
                              void* d_out, int out_size, void* d_ws, size_t ws_size,
                              hipStream_t stream) {
  (void)in_sizes; (void)n_in; (void)out_size; (void)ws_size;
  GruParams prm;
  // d_in order: 0:x, then f0(1-4), f1(5-8), b0(9-12), b1(13-16)
  prm.Wih[0] = (const float*)d_in[1];  prm.Whh[0] = (const float*)d_in[2];
  prm.bih[0] = (const float*)d_in[3];  prm.bhh[0] = (const float*)d_in[4];
  prm.Wih[2] = (const float*)d_in[5];  prm.Whh[2] = (const float*)d_in[6];
  prm.bih[2] = (const float*)d_in[7];  prm.bhh[2] = (const float*)d_in[8];
  prm.Wih[1] = (const float*)d_in[9];  prm.Whh[1] = (const float*)d_in[10];
  prm.bih[1] = (const float*)d_in[11]; prm.bhh[1] = (const float*)d_in[12];
  prm.Wih[3] = (const float*)d_in[13]; prm.Whh[3] = (const float*)d_in[14];
  prm.bih[3] = (const float*)d_in[15]; prm.bhh[3] = (const float*)d_in[16];

  const size_t XBF_BYTES  = (size_t)BB * TT * II * 2;      // 16 MiB
  const size_t HBUF_BYTES = (size_t)4 * 2 * BB * HH * 2;   // 512 KiB
  u16* xbf  = (u16*)d_ws;
  u16* hbuf = (u16*)((char*)d_ws + XBF_BYTES);
  u32* bar  = (u32*)((char*)d_ws + XBF_BYTES + HBUF_BYTES);

  prm.xbf = xbf; prm.hbuf = hbuf; prm.bar = bar; prm.out = (float*)d_out;

  // zero h state + barrier counters (poisoned 0xAA by harness; must be 0 each call)
  hipMemsetAsync((char*)d_ws + XBF_BYTES, 0, HBUF_BYTES + 4 * 64 * sizeof(u32), stream);

  const float* x = (const float*)d_in[0];
  cvt_x<<<dim3((BB * TT * II / 4) / 256), dim3(256), 0, stream>>>(x, xbf);

  void* args[] = { &prm };
  hipError_t err = hipLaunchCooperativeKernel((void*)gru_persist, dim3(256), dim3(256),
                                              args, 0, stream);
  if (err != hipSuccess) {
    // fallback: plain launch (grid == CU count, 1 WG/CU by resource usage)
    hipLaunchKernelGGL(gru_persist, dim3(256), dim3(256), 0, stream, prm);
  }
}

// Round 2
// 6030.270 us; speedup vs baseline: 1.0055x; 1.0055x over previous
//
#include <hip/hip_runtime.h>

#define HH 512
#define II 256
#define TT 512
#define BB 64

typedef unsigned short u16;
typedef unsigned int u32;
typedef __bf16 bf16x8 __attribute__((ext_vector_type(8)));
typedef u16 u16x8 __attribute__((ext_vector_type(8)));
typedef float f32x4 __attribute__((ext_vector_type(4)));

struct GruParams {
  const float* Wih[4];  // cell order: 0=f0, 1=b0, 2=f1, 3=b1
  const float* Whh[4];
  const float* bih[4];
  const float* bhh[4];
  const u16* xbf;   // [64][512][256] bf16
  u16* hbuf;        // [4 cells][2 parity][64][512] bf16
  u32* bar;         // [4 mm][2 pair][32] flags
  float* out;       // 64*512*1024 + 64*1024
};

__device__ __forceinline__ u16 f2bf(float f) {
  u32 u = __builtin_bit_cast(u32, f);
  u += 0x7fffu + ((u >> 16) & 1u);
  return (u16)(u >> 16);
}

__device__ __forceinline__ float sigm(float x) {
  return 1.0f / (1.0f + __expf(-x));
}

__device__ __forceinline__ float tanh_s(float x) {
  float t = __expf(-2.0f * fabsf(x));
  float r = (1.0f - t) / (1.0f + t);
  return copysignf(r, x);
}

__global__ void cvt_x(const float* __restrict__ x, u16* __restrict__ xb) {
  const int i = blockIdx.x * blockDim.x + threadIdx.x;
  const float4 v = reinterpret_cast<const float4*>(x)[i];
  ushort4 o;
  o.x = f2bf(v.x); o.y = f2bf(v.y); o.z = f2bf(v.z); o.w = f2bf(v.w);
  reinterpret_cast<ushort4*>(xb)[i] = o;
}

// 256 WGs: wg = cell(2b) | m(2b) | c(4b). 4 waves/WG: wid 0=r, 1=z, 2=i_n, 3=h_n.
__global__ __launch_bounds__(256, 1) void gru_persist(GruParams p) {
  const int tid  = threadIdx.x;
  const int lane = tid & 63;
  const int wid  = tid >> 6;
  const int wg   = blockIdx.x;
  const int cell = wg & 3;
  const int mm   = (wg >> 2) & 3;
  const int cc   = wg >> 4;
  const int KIN  = (cell < 2) ? II : HH;
  const int n16  = lane & 15;
  const int kg   = (lane >> 4) & 3;
  const int koff = kg * 8;
  const int gb   = (wid == 0) ? 0 : (wid == 1) ? HH : 2 * HH;
  const int nbase = gb + cc * 32;

  int nk, inp_end;
  if (wid < 2)       { nk = (KIN + HH) / 32; inp_end = KIN; }
  else if (wid == 2) { nk = KIN / 32;        inp_end = KIN; }
  else               { nk = HH / 32;         inp_end = 0;   }

  float bias0, bias1;
  {
    const int n0 = nbase + n16, n1 = nbase + 16 + n16;
    if (wid < 2)       { bias0 = p.bih[cell][n0] + p.bhh[cell][n0];
                         bias1 = p.bih[cell][n1] + p.bhh[cell][n1]; }
    else if (wid == 2) { bias0 = p.bih[cell][n0]; bias1 = p.bih[cell][n1]; }
    else               { bias0 = p.bhh[cell][n0]; bias1 = p.bhh[cell][n1]; }
  }

  // ---- persistent weight fragments in VGPRs/AGPRs: wf[ks][ntile], B[k][n] ----
  bf16x8 wf[32][2];
  {
    const float* Wih = p.Wih[cell];
    const float* Whh = p.Whh[cell];
    #pragma unroll
    for (int ks = 0; ks < 32; ++ks) {
      if (ks < nk) {
        const int kk = ks * 32;
        #pragma unroll
        for (int j = 0; j < 2; ++j) {
          const int r = nbase + 16 * j + n16;
          u16x8 t;
          if (kk < inp_end) {
            const int col = kk + koff;
            if (cell == 1) {  // b0: feature-flipped input -> flip Wih columns
              #pragma unroll
              for (int e = 0; e < 8; ++e)
                t[e] = f2bf(Wih[r * KIN + (KIN - 1 - (col + e))]);
            } else {
              const float4 a = *reinterpret_cast<const float4*>(Wih + r * KIN + col);
              const float4 b = *reinterpret_cast<const float4*>(Wih + r * KIN + col + 4);
              t[0]=f2bf(a.x); t[1]=f2bf(a.y); t[2]=f2bf(a.z); t[3]=f2bf(a.w);
              t[4]=f2bf(b.x); t[5]=f2bf(b.y); t[6]=f2bf(b.z); t[7]=f2bf(b.w);
            }
          } else {
            const int col = kk - inp_end + koff;
            const float4 a = *reinterpret_cast<const float4*>(Whh + r * HH + col);
            const float4 b = *reinterpret_cast<const float4*>(Whh + r * HH + col + 4);
            t[0]=f2bf(a.x); t[1]=f2bf(a.y); t[2]=f2bf(a.z); t[3]=f2bf(a.w);
            t[4]=f2bf(b.x); t[5]=f2bf(b.y); t[6]=f2bf(b.z); t[7]=f2bf(b.w);
          }
          wf[ks][j] = __builtin_bit_cast(bf16x8, t);
        }
        __builtin_amdgcn_sched_barrier(0);
      }
    }
  }

  __shared__ float gsm[4][16][33];  // pad 33: kills 4-way bank conflict
  // pair barrier: pairs (f0,f1)=pair0, (b0,b1)=pair1; 32 WGs/domain
  u32* fl = p.bar + (mm * 2 + (cell & 1)) * 32;
  const int wgl = ((cell >> 1) << 4) + cc;
  const int brow = mm * 16 + n16;   // this lane's A-operand batch row
  float h0r = 0.0f, h1r = 0.0f;     // fp32 master h for this thread's 2 elements

  for (int s = 0; s <= TT; ++s) {
    const int tc = (cell < 2) ? s : s - 1;   // layer-1 runs one step skewed
    const bool active = (tc >= 0) && (tc < TT);
    if (active) {
      const u16* inp_base = (cell < 2)
        ? p.xbf + (size_t)(brow * TT + tc) * II
        : p.hbuf + (size_t)(((cell - 2) * 2 + (tc & 1)) * BB + brow) * HH;
      const u16* own_base =
          p.hbuf + (size_t)((cell * 2 + ((tc & 1) ^ 1)) * BB + brow) * HH;

      f32x4 acc00 = {bias0, bias0, bias0, bias0};
      f32x4 acc01 = {bias1, bias1, bias1, bias1};
      f32x4 acc10 = {0.f, 0.f, 0.f, 0.f};
      f32x4 acc11 = {0.f, 0.f, 0.f, 0.f};

      #pragma unroll
      for (int blk = 0; blk < 4; ++blk) {
        if (blk * 256 < nk * 32) {
          const int kb = blk * 256;
          const u16* bp = (kb < inp_end) ? (inp_base + kb + koff)
                                         : (own_base + (kb - inp_end) + koff);
          #pragma unroll
          for (int u = 0; u < 8; ++u) {
            const bf16x8 af = __builtin_bit_cast(bf16x8,
                *reinterpret_cast<const uint4*>(bp + u * 32));
            if (u & 1) {
              acc10 = __builtin_amdgcn_mfma_f32_16x16x32_bf16(af, wf[blk*8+u][0], acc10, 0, 0, 0);
              acc11 = __builtin_amdgcn_mfma_f32_16x16x32_bf16(af, wf[blk*8+u][1], acc11, 0, 0, 0);
            } else {
              acc00 = __builtin_amdgcn_mfma_f32_16x16x32_bf16(af, wf[blk*8+u][0], acc00, 0, 0, 0);
              acc01 = __builtin_amdgcn_mfma_f32_16x16x32_bf16(af, wf[blk*8+u][1], acc01, 0, 0, 0);
            }
          }
        }
      }
      #pragma unroll
      for (int i = 0; i < 4; ++i) {
        gsm[wid][kg * 4 + i][n16]      = acc00[i] + acc10[i];
        gsm[wid][kg * 4 + i][16 + n16] = acc01[i] + acc11[i];
      }
    }
    __syncthreads();
    if (active) {
      #pragma unroll
      for (int q = 0; q < 2; ++q) {
        const int e = tid + q * 256;
        const int row = e >> 5, col = e & 31;
        const float rr = sigm(gsm[0][row][col]);
        const float zz = sigm(gsm[1][row][col]);
        const float nn = tanh_s(gsm[2][row][col] + rr * gsm[3][row][col]);
        const float hp = q ? h1r : h0r;
        const float hn = (1.0f - zz) * nn + zz * hp;
        if (q) h1r = hn; else h0r = hn;
        const int gbrow = mm * 16 + row;
        const int hc = cc * 32 + col;
        p.hbuf[(size_t)((cell * 2 + (tc & 1)) * BB + gbrow) * HH + hc] = f2bf(hn);
        if (cell >= 2) {
          const int jb = (cell == 2) ? hc : HH + hc;
          __builtin_nontemporal_store(hn,
              p.out + (size_t)(gbrow * TT + tc) * 1024 + jb);
          if (tc == TT - 1)
            p.out[(size_t)BB * TT * 1024 + (size_t)gbrow * 1024 + jb] = hn;
        }
      }
    }
    // ---- pair barrier (32 WGs): per-WG release flag store, parallel spin ----
    __syncthreads();
    if (s < TT) {
      if (wid == 0) {
        const u32 tgt = (u32)(s + 1);
        if (lane == 0)
          __hip_atomic_store(&fl[wgl], tgt, __ATOMIC_RELEASE, __HIP_MEMORY_SCOPE_AGENT);
        if (lane < 32) {
          while (__hip_atomic_load(&fl[lane], __ATOMIC_RELAXED, __HIP_MEMORY_SCOPE_AGENT) < tgt)
            __builtin_amdgcn_s_sleep(1);
        }
        (void)__hip_atomic_load(&fl[0], __ATOMIC_ACQUIRE, __HIP_MEMORY_SCOPE_AGENT);
      }
      __syncthreads();
    }
  }
}

extern "C" void kernel_launch(void* const* d_in, const int* in_sizes, int n_in,
                              void* d_out, int out_size, void* d_ws, size_t ws_size,
                              hipStream_t stream) {
  (void)in_sizes; (void)n_in; (void)out_size; (void)ws_size;
  GruParams prm;
  // d_in order: 0:x, then f0(1-4), f1(5-8), b0(9-12), b1(13-16)
  prm.Wih[0] = (const float*)d_in[1];  prm.Whh[0] = (const float*)d_in[2];
  prm.bih[0] = (const float*)d_in[3];  prm.bhh[0] = (const float*)d_in[4];
  prm.Wih[2] = (const float*)d_in[5];  prm.Whh[2] = (const float*)d_in[6];
  prm.bih[2] = (const float*)d_in[7];  prm.bhh[2] = (const float*)d_in[8];
  prm.Wih[1] = (const float*)d_in[9];  prm.Whh[1] = (const float*)d_in[10];
  prm.bih[1] = (const float*)d_in[11]; prm.bhh[1] = (const float*)d_in[12];
  prm.Wih[3] = (const float*)d_in[13]; prm.Whh[3] = (const float*)d_in[14];
  prm.bih[3] = (const float*)d_in[15]; prm.bhh[3] = (const float*)d_in[16];

  const size_t XBF_BYTES  = (size_t)BB * TT * II * 2;      // 16 MiB
  const size_t HBUF_BYTES = (size_t)4 * 2 * BB * HH * 2;   // 512 KiB
  u16* xbf  = (u16*)d_ws;
  u16* hbuf = (u16*)((char*)d_ws + XBF_BYTES);
  u32* bar  = (u32*)((char*)d_ws + XBF_BYTES + HBUF_BYTES);

  prm.xbf = xbf; prm.hbuf = hbuf; prm.bar = bar; prm.out = (float*)d_out;

  // zero h state + barrier flags (poisoned 0xAA by harness; must be 0 each call)
  hipMemsetAsync((char*)d_ws + XBF_BYTES, 0, HBUF_BYTES + 4 * 2 * 32 * sizeof(u32), stream);

  const float* x = (const float*)d_in[0];
  cvt_x<<<dim3((BB * TT * II / 4) / 256), dim3(256), 0, stream>>>(x, xbf);

  void* args[] = { &prm };
  hipError_t err = hipLaunchCooperativeKernel((void*)gru_persist, dim3(256), dim3(256),
                                              args, 0, stream);
  if (err != hipSuccess) {
    // fallback: plain launch (grid == CU count, 1 WG/CU by resource usage)
    hipLaunchKernelGGL(gru_persist, dim3(256), dim3(256), 0, stream, prm);
  }
}

// Round 4
// 2973.783 us; speedup vs baseline: 2.0391x; 2.0278x over previous
//
#include <hip/hip_runtime.h>

#define HH 512
#define II 256
#define TT 512
#define BB 64

typedef unsigned short u16;
typedef unsigned int u32;
typedef unsigned long long u64;
typedef __bf16 bf16x8 __attribute__((ext_vector_type(8)));
typedef u16 u16x8 __attribute__((ext_vector_type(8)));
typedef float f32x4 __attribute__((ext_vector_type(4)));

struct GruParams {
  const float* Wih[4];  // cell order: 0=f0, 1=b0, 2=f1, 3=b1
  const float* Whh[4];
  const float* bih[4];
  const float* bhh[4];
  const u16* xbf;   // [64][512][256] bf16 (immutable after cvt_x)
  u16* hbuf;        // [4 cells][2 parity][64][512] bf16
  u32* bar;         // [0..255] per-XCD flags; [256] ctr; [257..512] xcds
  float* out;       // 64*512*1024 + 64*1024
};

__device__ __forceinline__ u16 f2bf(float f) {
  u32 u = __builtin_bit_cast(u32, f);
  u += 0x7fffu + ((u >> 16) & 1u);
  return (u16)(u >> 16);
}

__device__ __forceinline__ float sigm(float x) {
  return 1.0f / (1.0f + __expf(-x));
}

__device__ __forceinline__ float tanh_s(float x) {
  float t = __expf(-2.0f * fabsf(x));
  float r = (1.0f - t) / (1.0f + t);
  return copysignf(r, x);
}

__global__ void cvt_x(const float* __restrict__ x, u16* __restrict__ xb) {
  const int i = blockIdx.x * blockDim.x + threadIdx.x;
  const float4 v = reinterpret_cast<const float4*>(x)[i];
  ushort4 o;
  o.x = f2bf(v.x); o.y = f2bf(v.y); o.z = f2bf(v.z); o.w = f2bf(v.w);
  reinterpret_cast<ushort4*>(xb)[i] = o;
}

// 256 WGs, 1/CU (LDS-forced). Roles derived from measured XCD so that each
// (pair, mm) sync domain = the 32 WGs of ONE XCD -> all cross-WG traffic is
// same-XCD L2 (hardware-coherent). 4 waves/WG: wid 0=r, 1=z, 2=i_n, 3=h_n.
__global__ __launch_bounds__(256, 1) void gru_persist(GruParams p) {
  const int tid  = threadIdx.x;
  const int lane = tid & 63;
  const int wid  = tid >> 6;

  __shared__ char lds_force[90112];   // forces 1 WG/CU (2x96KB > 160KB)
  __shared__ float gsm[4][16][33];    // pad 33: no bank conflicts
  __shared__ u32 role_sm;

  // ---- discovery: measure physical XCD, group same-XCD WGs ----
  u32 xcd;
  asm volatile("s_getreg_b32 %0, hwreg(HW_REG_XCC_ID)" : "=s"(xcd));
  xcd &= 7u;
  u32* ctr  = p.bar + 256;
  u32* xcds = p.bar + 257;
  if (tid == 0) xcds[blockIdx.x] = xcd;
  __syncthreads();
  if (tid == 0) {
    __hip_atomic_fetch_add(ctr, 1u, __ATOMIC_RELEASE, __HIP_MEMORY_SCOPE_AGENT);
    while (__hip_atomic_load(ctr, __ATOMIC_RELAXED, __HIP_MEMORY_SCOPE_AGENT) < 256u) {}
    (void)__hip_atomic_load(ctr, __ATOMIC_ACQUIRE, __HIP_MEMORY_SCOPE_AGENT);
    u32 rank = 0;
    for (int w = 0; w < 256; ++w) {
      const u32 xw = xcds[w];
      if (xw == xcd && w < (int)blockIdx.x) rank++;
    }
    role_sm = rank;
  }
  __syncthreads();
  if (p.xbf == nullptr) lds_force[tid] = 1;  // opaque: keep LDS allocation

  const u32 rank = role_sm;                    // 0..31 within this XCD
  const int cell = (xcd < 4) ? (rank < 16 ? 0 : 2) : (rank < 16 ? 1 : 3);
  const int mm   = (int)(xcd & 3u);
  const int cc   = (int)(rank & 15u);
  const int wgl  = (int)rank;

  const int KIN  = (cell < 2) ? II : HH;
  const int n16  = lane & 15;
  const int kg   = (lane >> 4) & 3;
  const int koff = kg * 8;
  const int gb   = (wid == 0) ? 0 : (wid == 1) ? HH : 2 * HH;
  const int nbase = gb + cc * 32;

  int nk, inp_end;
  if (wid < 2)       { nk = (KIN + HH) / 32; inp_end = KIN; }
  else if (wid == 2) { nk = KIN / 32;        inp_end = KIN; }
  else               { nk = HH / 32;         inp_end = 0;   }

  float bias0, bias1;
  {
    const int n0 = nbase + n16, n1 = nbase + 16 + n16;
    if (wid < 2)       { bias0 = p.bih[cell][n0] + p.bhh[cell][n0];
                         bias1 = p.bih[cell][n1] + p.bhh[cell][n1]; }
    else if (wid == 2) { bias0 = p.bih[cell][n0]; bias1 = p.bih[cell][n1]; }
    else               { bias0 = p.bhh[cell][n0]; bias1 = p.bhh[cell][n1]; }
  }

  // ---- persistent weight fragments: wf[ks][ntile], B[k][n] layout ----
  bf16x8 wf[32][2];
  {
    const float* Wih = p.Wih[cell];
    const float* Whh = p.Whh[cell];
    #pragma unroll
    for (int ks = 0; ks < 32; ++ks) {
      if (ks < nk) {
        const int kk = ks * 32;
        #pragma unroll
        for (int j = 0; j < 2; ++j) {
          const int r = nbase + 16 * j + n16;
          u16x8 t;
          if (kk < inp_end) {
            const int col = kk + koff;
            if (cell == 1) {  // b0: feature-flipped input -> flip Wih columns
              #pragma unroll
              for (int e = 0; e < 8; ++e)
                t[e] = f2bf(Wih[r * KIN + (KIN - 1 - (col + e))]);
            } else {
              const float4 a = *reinterpret_cast<const float4*>(Wih + r * KIN + col);
              const float4 b = *reinterpret_cast<const float4*>(Wih + r * KIN + col + 4);
              t[0]=f2bf(a.x); t[1]=f2bf(a.y); t[2]=f2bf(a.z); t[3]=f2bf(a.w);
              t[4]=f2bf(b.x); t[5]=f2bf(b.y); t[6]=f2bf(b.z); t[7]=f2bf(b.w);
            }
          } else {
            const int col = kk - inp_end + koff;
            const float4 a = *reinterpret_cast<const float4*>(Whh + r * HH + col);
            const float4 b = *reinterpret_cast<const float4*>(Whh + r * HH + col + 4);
            t[0]=f2bf(a.x); t[1]=f2bf(a.y); t[2]=f2bf(a.z); t[3]=f2bf(a.w);
            t[4]=f2bf(b.x); t[5]=f2bf(b.y); t[6]=f2bf(b.z); t[7]=f2bf(b.w);
          }
          wf[ks][j] = __builtin_bit_cast(bf16x8, t);
        }
        __builtin_amdgcn_sched_barrier(0);
      }
    }
  }

  u32* fl = p.bar + xcd * 32;       // this XCD's 32 barrier flags (live in L2)
  const int brow = mm * 16 + n16;   // this lane's A-operand batch row
  float h0r = 0.0f, h1r = 0.0f;     // fp32 master h for this thread's 2 elements

  for (int s = 0; s <= TT; ++s) {
    const int tc = (cell < 2) ? s : s - 1;   // layer-1 runs one step skewed
    const bool active = (tc >= 0) && (tc < TT);
    if (active) {
      const u16* inp_base = (cell < 2)
        ? p.xbf + (size_t)(brow * TT + tc) * II
        : p.hbuf + (size_t)(((cell - 2) * 2 + (tc & 1)) * BB + brow) * HH;
      const u16* own_base =
          p.hbuf + (size_t)((cell * 2 + ((tc & 1) ^ 1)) * BB + brow) * HH;

      f32x4 acc00 = {bias0, bias0, bias0, bias0};
      f32x4 acc01 = {bias1, bias1, bias1, bias1};
      f32x4 acc10 = {0.f, 0.f, 0.f, 0.f};
      f32x4 acc11 = {0.f, 0.f, 0.f, 0.f};

      #pragma unroll
      for (int blk = 0; blk < 4; ++blk) {
        if (blk * 256 < nk * 32) {
          const int kb = blk * 256;
          const u16* bp = (kb < inp_end) ? (inp_base + kb + koff)
                                         : (own_base + (kb - inp_end) + koff);
          #pragma unroll
          for (int u = 0; u < 8; ++u) {
            const bf16x8 af = __builtin_bit_cast(bf16x8,
                *reinterpret_cast<const uint4*>(bp + u * 32));
            if (u & 1) {
              acc10 = __builtin_amdgcn_mfma_f32_16x16x32_bf16(af, wf[blk*8+u][0], acc10, 0, 0, 0);
              acc11 = __builtin_amdgcn_mfma_f32_16x16x32_bf16(af, wf[blk*8+u][1], acc11, 0, 0, 0);
            } else {
              acc00 = __builtin_amdgcn_mfma_f32_16x16x32_bf16(af, wf[blk*8+u][0], acc00, 0, 0, 0);
              acc01 = __builtin_amdgcn_mfma_f32_16x16x32_bf16(af, wf[blk*8+u][1], acc01, 0, 0, 0);
            }
          }
        }
      }
      #pragma unroll
      for (int i = 0; i < 4; ++i) {
        gsm[wid][kg * 4 + i][n16]      = acc00[i] + acc10[i];
        gsm[wid][kg * 4 + i][16 + n16] = acc01[i] + acc11[i];
      }
    }
    __syncthreads();
    if (active) {
      #pragma unroll
      for (int q = 0; q < 2; ++q) {
        const int e = tid + q * 256;
        const int row = e >> 5, col = e & 31;
        const float rr = sigm(gsm[0][row][col]);
        const float zz = sigm(gsm[1][row][col]);
        const float nn = tanh_s(gsm[2][row][col] + rr * gsm[3][row][col]);
        const float hp = q ? h1r : h0r;
        const float hn = (1.0f - zz) * nn + zz * hp;
        if (q) h1r = hn; else h0r = hn;
        const int gbrow = mm * 16 + row;
        const int hc = cc * 32 + col;
        // normal store: write-through L1 -> lands in this XCD's L2 (coherent
        // for all 32 consumer WGs, which are on this XCD by construction)
        p.hbuf[(size_t)((cell * 2 + (tc & 1)) * BB + gbrow) * HH + hc] = f2bf(hn);
      }
    }
    // ---- same-XCD step barrier: vmcnt(0) (stores acked at L2), flag store,
    //      poll via L2 atomics (bypass L1), then L1-only invalidate ----
    if (s < TT) {
      asm volatile("s_waitcnt vmcnt(0)" ::: "memory");
      __syncthreads();
      if (wid == 0) {
        const u32 tgt = (u32)(s + 1);
        if (lane == 0)
          (void)__hip_atomic_exchange(&fl[wgl], tgt, __ATOMIC_RELAXED,
                                      __HIP_MEMORY_SCOPE_WORKGROUP);
        if (lane < 32) {
          const u64 fa = (u64)(uintptr_t)&fl[lane];
          u32 old;
          do {
            asm volatile("global_atomic_add %0, %1, %2, off sc0\n\t"
                         "s_waitcnt vmcnt(0)"
                         : "=v"(old) : "v"(fa), "v"(0u) : "memory");
          } while (old < tgt);
        }
        asm volatile("buffer_inv sc0" ::: "memory");  // L1-only invalidate
      }
      __syncthreads();
    }
    // ---- out stores AFTER the barrier: HBM ack hides under next compute ----
    if (active && cell >= 2) {
      #pragma unroll
      for (int q = 0; q < 2; ++q) {
        const int e = tid + q * 256;
        const int row = e >> 5, col = e & 31;
        const int gbrow = mm * 16 + row;
        const int jb = ((cell == 2) ? 0 : HH) + cc * 32 + col;
        const float hv = q ? h1r : h0r;
        __builtin_nontemporal_store(hv,
            p.out + (size_t)(gbrow * TT + tc) * 1024 + jb);
        if (tc == TT - 1)
          p.out[(size_t)BB * TT * 1024 + (size_t)gbrow * 1024 + jb] = hv;
      }
    }
  }
}

extern "C" void kernel_launch(void* const* d_in, const int* in_sizes, int n_in,
                              void* d_out, int out_size, void* d_ws, size_t ws_size,
                              hipStream_t stream) {
  (void)in_sizes; (void)n_in; (void)out_size; (void)ws_size;
  GruParams prm;
  // d_in order: 0:x, then f0(1-4), f1(5-8), b0(9-12), b1(13-16)
  prm.Wih[0] = (const float*)d_in[1];  prm.Whh[0] = (const float*)d_in[2];
  prm.bih[0] = (const float*)d_in[3];  prm.bhh[0] = (const float*)d_in[4];
  prm.Wih[2] = (const float*)d_in[5];  prm.Whh[2] = (const float*)d_in[6];
  prm.bih[2] = (const float*)d_in[7];  prm.bhh[2] = (const float*)d_in[8];
  prm.Wih[1] = (const float*)d_in[9];  prm.Whh[1] = (const float*)d_in[10];
  prm.bih[1] = (const float*)d_in[11]; prm.bhh[1] = (const float*)d_in[12];
  prm.Wih[3] = (const float*)d_in[13]; prm.Whh[3] = (const float*)d_in[14];
  prm.bih[3] = (const float*)d_in[15]; prm.bhh[3] = (const float*)d_in[16];

  const size_t XBF_BYTES  = (size_t)BB * TT * II * 2;      // 16 MiB
  const size_t HBUF_BYTES = (size_t)4 * 2 * BB * HH * 2;   // 512 KiB
  u16* xbf  = (u16*)d_ws;
  u16* hbuf = (u16*)((char*)d_ws + XBF_BYTES);
  u32* bar  = (u32*)((char*)d_ws + XBF_BYTES + HBUF_BYTES);

  prm.xbf = xbf; prm.hbuf = hbuf; prm.bar = bar; prm.out = (float*)d_out;

  // zero h state + flags + ctr + xcds table (re-zeroed every replay)
  hipMemsetAsync((char*)d_ws + XBF_BYTES, 0, HBUF_BYTES + 4096, stream);

  const float* x = (const float*)d_in[0];
  cvt_x<<<dim3((BB * TT * II / 4) / 256), dim3(256), 0, stream>>>(x, xbf);

  void* args[] = { &prm };
  hipError_t err = hipLaunchCooperativeKernel((void*)gru_persist, dim3(256), dim3(256),
                                              args, 0, stream);
  if (err != hipSuccess) {
    // fallback: plain launch (1 WG/CU by LDS -> all 256 co-resident anyway)
    hipLaunchKernelGGL(gru_persist, dim3(256), dim3(256), 0, stream, prm);
  }
}

// Round 6
// 2608.493 us; speedup vs baseline: 2.3246x; 1.1400x over previous
//
#include <hip/hip_runtime.h>

#define HH 512
#define II 256
#define TT 512
#define BB 64

typedef unsigned short u16;
typedef unsigned int u32;
typedef unsigned long long u64;
typedef __bf16 bf16x8 __attribute__((ext_vector_type(8)));
typedef u16 u16x8 __attribute__((ext_vector_type(8)));
typedef float f32x4 __attribute__((ext_vector_type(4)));

struct GruParams {
  const float* Wih[4];  // cell order: 0=f0, 1=b0, 2=f1, 3=b1
  const float* Whh[4];
  const float* bih[4];
  const float* bhh[4];
  const u16* xbf;   // [64][512][256] bf16 (immutable after cvt_x)
  u16* hbuf;        // [4 cells][2 parity][64][512] bf16
  u32* bar;         // [xcd*32]: per-XCD step counter (1 line each); [256] ctr; [257..512] xcds
  float* out;       // 64*512*1024 + 64*1024
};

__device__ __forceinline__ u16 f2bf(float f) {
  u32 u = __builtin_bit_cast(u32, f);
  u += 0x7fffu + ((u >> 16) & 1u);
  return (u16)(u >> 16);
}

__device__ __forceinline__ float sigm(float x) {
  return 1.0f / (1.0f + __expf(-x));
}

__device__ __forceinline__ float tanh_s(float x) {
  float t = __expf(-2.0f * fabsf(x));
  float r = (1.0f - t) / (1.0f + t);
  return copysignf(r, x);
}

__global__ void cvt_x(const float* __restrict__ x, u16* __restrict__ xb) {
  const int i = blockIdx.x * blockDim.x + threadIdx.x;
  const float4 v = reinterpret_cast<const float4*>(x)[i];
  ushort4 o;
  o.x = f2bf(v.x); o.y = f2bf(v.y); o.z = f2bf(v.z); o.w = f2bf(v.w);
  reinterpret_cast<ushort4*>(xb)[i] = o;
}

// 256 WGs (R4 config: no forced LDS). Roles derived from measured XCD so each
// (pair, mm) sync domain = the 32 WGs of ONE XCD -> all cross-WG traffic is
// same-XCD L2 (hardware-coherent). 4 waves: wid 0=r,1=z,2=i_n,3=h_n.
__global__ __launch_bounds__(256, 1) void gru_persist(GruParams p) {
  const int tid  = threadIdx.x;
  const int lane = tid & 63;
  const int wid  = tid >> 6;

  __shared__ float gsm[4][16][33];    // pad 33
  __shared__ u32 role_sm;

  // ---- discovery: measure physical XCD, group same-XCD WGs ----
  u32 xcd;
  asm volatile("s_getreg_b32 %0, hwreg(HW_REG_XCC_ID)" : "=s"(xcd));
  xcd &= 7u;
  u32* ctr  = p.bar + 256;
  u32* xcds = p.bar + 257;
  if (tid == 0) xcds[blockIdx.x] = xcd;
  __syncthreads();
  if (tid == 0) {
    __hip_atomic_fetch_add(ctr, 1u, __ATOMIC_RELEASE, __HIP_MEMORY_SCOPE_AGENT);
    while (__hip_atomic_load(ctr, __ATOMIC_RELAXED, __HIP_MEMORY_SCOPE_AGENT) < 256u) {}
    (void)__hip_atomic_load(ctr, __ATOMIC_ACQUIRE, __HIP_MEMORY_SCOPE_AGENT);
    u32 rank = 0;
    for (int w = 0; w < 256; ++w) {
      const u32 xw = xcds[w];
      if (xw == xcd && w < (int)blockIdx.x) rank++;
    }
    role_sm = rank;
  }
  __syncthreads();

  const u32 rank = role_sm;                    // 0..31 within this XCD
  const int cell = (xcd < 4) ? (rank < 16 ? 0 : 2) : (rank < 16 ? 1 : 3);
  const int mm   = (int)(xcd & 3u);
  const int cc   = (int)(rank & 15u);

  const int KIN  = (cell < 2) ? II : HH;
  const int n16  = lane & 15;
  const int kg   = (lane >> 4) & 3;
  const int koff = kg * 8;
  const int gb   = (wid == 0) ? 0 : (wid == 1) ? HH : 2 * HH;
  const int nbase = gb + cc * 32;

  int nk, inp_end;
  if (wid < 2)       { nk = (KIN + HH) / 32; inp_end = KIN; }
  else if (wid == 2) { nk = KIN / 32;        inp_end = KIN; }
  else               { nk = HH / 32;         inp_end = 0;   }

  float bias0, bias1;
  {
    const int n0 = nbase + n16, n1 = nbase + 16 + n16;
    if (wid < 2)       { bias0 = p.bih[cell][n0] + p.bhh[cell][n0];
                         bias1 = p.bih[cell][n1] + p.bhh[cell][n1]; }
    else if (wid == 2) { bias0 = p.bih[cell][n0]; bias1 = p.bih[cell][n1]; }
    else               { bias0 = p.bhh[cell][n0]; bias1 = p.bhh[cell][n1]; }
  }

  // ---- persistent weight fragments: wf[ks][ntile], B[k][n] layout ----
  bf16x8 wf[32][2];
  {
    const float* Wih = p.Wih[cell];
    const float* Whh = p.Whh[cell];
    #pragma unroll
    for (int ks = 0; ks < 32; ++ks) {
      if (ks < nk) {
        const int kk = ks * 32;
        #pragma unroll
        for (int j = 0; j < 2; ++j) {
          const int r = nbase + 16 * j + n16;
          u16x8 t;
          if (kk < inp_end) {
            const int col = kk + koff;
            if (cell == 1) {  // b0: feature-flipped input -> flip Wih columns
              #pragma unroll
              for (int e = 0; e < 8; ++e)
                t[e] = f2bf(Wih[r * KIN + (KIN - 1 - (col + e))]);
            } else {
              const float4 a = *reinterpret_cast<const float4*>(Wih + r * KIN + col);
              const float4 b = *reinterpret_cast<const float4*>(Wih + r * KIN + col + 4);
              t[0]=f2bf(a.x); t[1]=f2bf(a.y); t[2]=f2bf(a.z); t[3]=f2bf(a.w);
              t[4]=f2bf(b.x); t[5]=f2bf(b.y); t[6]=f2bf(b.z); t[7]=f2bf(b.w);
            }
          } else {
            const int col = kk - inp_end + koff;
            const float4 a = *reinterpret_cast<const float4*>(Whh + r * HH + col);
            const float4 b = *reinterpret_cast<const float4*>(Whh + r * HH + col + 4);
            t[0]=f2bf(a.x); t[1]=f2bf(a.y); t[2]=f2bf(a.z); t[3]=f2bf(a.w);
            t[4]=f2bf(b.x); t[5]=f2bf(b.y); t[6]=f2bf(b.z); t[7]=f2bf(b.w);
          }
          wf[ks][j] = __builtin_bit_cast(bf16x8, t);
        }
        __builtin_amdgcn_sched_barrier(0);
      }
    }
  }

  u32* dctr = p.bar + xcd * 32;     // this XCD's step counter: own 128B line
  const int brow = mm * 16 + n16;   // this lane's A-operand batch row
  float h0r = 0.0f, h1r = 0.0f;     // fp32 master h for this thread's 2 elements

  for (int s = 0; s <= TT; ++s) {
    const int tc = (cell < 2) ? s : s - 1;   // layer-1 runs one step skewed
    const bool active = (tc >= 0) && (tc < TT);
    if (active) {
      const u16* inp_base = (cell < 2)
        ? p.xbf + (size_t)(brow * TT + tc) * II
        : p.hbuf + (size_t)(((cell - 2) * 2 + (tc & 1)) * BB + brow) * HH;
      const u16* own_base =
          p.hbuf + (size_t)((cell * 2 + ((tc & 1) ^ 1)) * BB + brow) * HH;

      f32x4 acc00 = {bias0, bias0, bias0, bias0};
      f32x4 acc01 = {bias1, bias1, bias1, bias1};
      f32x4 acc10 = {0.f, 0.f, 0.f, 0.f};
      f32x4 acc11 = {0.f, 0.f, 0.f, 0.f};

      #pragma unroll
      for (int blk = 0; blk < 4; ++blk) {
        if (blk * 256 < nk * 32) {
          const int kb = blk * 256;
          const u16* bp = (kb < inp_end) ? (inp_base + kb + koff)
                                         : (own_base + (kb - inp_end) + koff);
          #pragma unroll
          for (int u = 0; u < 8; ++u) {
            const bf16x8 af = __builtin_bit_cast(bf16x8,
                *reinterpret_cast<const uint4*>(bp + u * 32));
            if (u & 1) {
              acc10 = __builtin_amdgcn_mfma_f32_16x16x32_bf16(af, wf[blk*8+u][0], acc10, 0, 0, 0);
              acc11 = __builtin_amdgcn_mfma_f32_16x16x32_bf16(af, wf[blk*8+u][1], acc11, 0, 0, 0);
            } else {
              acc00 = __builtin_amdgcn_mfma_f32_16x16x32_bf16(af, wf[blk*8+u][0], acc00, 0, 0, 0);
              acc01 = __builtin_amdgcn_mfma_f32_16x16x32_bf16(af, wf[blk*8+u][1], acc01, 0, 0, 0);
            }
          }
        }
      }
      #pragma unroll
      for (int i = 0; i < 4; ++i) {
        gsm[wid][kg * 4 + i][n16]      = acc00[i] + acc10[i];
        gsm[wid][kg * 4 + i][16 + n16] = acc01[i] + acc11[i];
      }
    }
    __syncthreads();
    if (active) {
      #pragma unroll
      for (int q = 0; q < 2; ++q) {
        const int e = tid + q * 256;
        const int row = e >> 5, col = e & 31;
        const float rr = sigm(gsm[0][row][col]);
        const float zz = sigm(gsm[1][row][col]);
        const float nn = tanh_s(gsm[2][row][col] + rr * gsm[3][row][col]);
        const float hp = q ? h1r : h0r;
        const float hn = (1.0f - zz) * nn + zz * hp;
        if (q) h1r = hn; else h0r = hn;
        const int gbrow = mm * 16 + row;
        const int hc = cc * 32 + col;
        // normal store: write-through L1 -> lands in this XCD's L2 (coherent
        // for all 32 consumer WGs, which are on this XCD by construction)
        p.hbuf[(size_t)((cell * 2 + (tc & 1)) * BB + gbrow) * HH + hc] = f2bf(hn);
      }
    }
    // ---- same-XCD step barrier: vmcnt(0) (stores acked at L2), ONE atomic
    //      arrival per WG, ONE polling lane per WG on a single counter word
    //      (atomics/atomic-loads execute at L2 -> no stale-L1 spin), then
    //      L1-only invalidate so consumer loads refetch from L2 ----
    if (s < TT) {
      asm volatile("s_waitcnt vmcnt(0)" ::: "memory");
      __syncthreads();
      if (wid == 0) {
        if (lane == 0) {
          (void)__hip_atomic_fetch_add(dctr, 1u, __ATOMIC_RELAXED,
                                       __HIP_MEMORY_SCOPE_AGENT);
          const u32 tgt = 32u * (u32)(s + 1);
          while (__hip_atomic_load(dctr, __ATOMIC_RELAXED,
                                   __HIP_MEMORY_SCOPE_AGENT) < tgt) {}
        }
        asm volatile("buffer_inv sc0" ::: "memory");  // L1-only invalidate
      }
      __syncthreads();
    }
    // ---- out stores AFTER the barrier: HBM ack hides under next compute ----
    if (active && cell >= 2) {
      #pragma unroll
      for (int q = 0; q < 2; ++q) {
        const int e = tid + q * 256;
        const int row = e >> 5, col = e & 31;
        const int gbrow = mm * 16 + row;
        const int jb = ((cell == 2) ? 0 : HH) + cc * 32 + col;
        const float hv = q ? h1r : h0r;
        __builtin_nontemporal_store(hv,
            p.out + (size_t)(gbrow * TT + tc) * 1024 + jb);
        if (tc == TT - 1)
          p.out[(size_t)BB * TT * 1024 + (size_t)gbrow * 1024 + jb] = hv;
      }
    }
  }
}

extern "C" void kernel_launch(void* const* d_in, const int* in_sizes, int n_in,
                              void* d_out, int out_size, void* d_ws, size_t ws_size,
                              hipStream_t stream) {
  (void)in_sizes; (void)n_in; (void)out_size; (void)ws_size;
  GruParams prm;
  // d_in order: 0:x, then f0(1-4), f1(5-8), b0(9-12), b1(13-16)
  prm.Wih[0] = (const float*)d_in[1];  prm.Whh[0] = (const float*)d_in[2];
  prm.bih[0] = (const float*)d_in[3];  prm.bhh[0] = (const float*)d_in[4];
  prm.Wih[2] = (const float*)d_in[5];  prm.Whh[2] = (const float*)d_in[6];
  prm.bih[2] = (const float*)d_in[7];  prm.bhh[2] = (const float*)d_in[8];
  prm.Wih[1] = (const float*)d_in[9];  prm.Whh[1] = (const float*)d_in[10];
  prm.bih[1] = (const float*)d_in[11]; prm.bhh[1] = (const float*)d_in[12];
  prm.Wih[3] = (const float*)d_in[13]; prm.Whh[3] = (const float*)d_in[14];
  prm.bih[3] = (const float*)d_in[15]; prm.bhh[3] = (const float*)d_in[16];

  const size_t XBF_BYTES  = (size_t)BB * TT * II * 2;      // 16 MiB
  const size_t HBUF_BYTES = (size_t)4 * 2 * BB * HH * 2;   // 512 KiB
  u16* xbf  = (u16*)d_ws;
  u16* hbuf = (u16*)((char*)d_ws + XBF_BYTES);
  u32* bar  = (u32*)((char*)d_ws + XBF_BYTES + HBUF_BYTES);

  prm.xbf = xbf; prm.hbuf = hbuf; prm.bar = bar; prm.out = (float*)d_out;

  // zero h state + counters + xcds table (re-zeroed every replay)
  hipMemsetAsync((char*)d_ws + XBF_BYTES, 0, HBUF_BYTES + 4096, stream);

  const float* x = (const float*)d_in[0];
  cvt_x<<<dim3((BB * TT * II / 4) / 256), dim3(256), 0, stream>>>(x, xbf);

  void* args[] = { &prm };
  hipError_t err = hipLaunchCooperativeKernel((void*)gru_persist, dim3(256), dim3(256),
                                              args, 0, stream);
  if (err != hipSuccess) {
    // fallback: plain launch (256 WGs on 256 CUs -> co-resident)
    hipLaunchKernelGGL(gru_persist, dim3(256), dim3(256), 0, stream, prm);
  }
}